// Round 8
// baseline (95.378 us; speedup 1.0000x reference)
//
#include <hip/hip_runtime.h>
#include <math.h>

// Problem sizes (fixed): B=4, N=512, M=512, D=256
#define BB 4
#define NN 512
#define MM 512
#define DD 256

typedef short  s16x8 __attribute__((ext_vector_type(8)));
typedef __bf16 bf16x8 __attribute__((ext_vector_type(8)));
typedef float  f32x4 __attribute__((ext_vector_type(4)));
typedef unsigned short u16x4 __attribute__((ext_vector_type(4)));

static __device__ __forceinline__ f32x4 mfma16(s16x8 a, s16x8 b, f32x4 c) {
    return __builtin_amdgcn_mfma_f32_16x16x32_bf16(
        __builtin_bit_cast(bf16x8, a), __builtin_bit_cast(bf16x8, b), c, 0, 0, 0);
}

// f32 -> bf16 round-to-nearest-even
static __device__ __forceinline__ unsigned short f2b(float f) {
    union { float f; unsigned u; } v; v.f = f;
    unsigned r = v.u + 0x7FFFu + ((v.u >> 16) & 1u);
    return (unsigned short)(r >> 16);
}

// load 8 consecutive f32 (32B-aligned) -> bf16 MFMA fragment
static __device__ __forceinline__ s16x8 cvt8(const float* __restrict__ p) {
    const float4 a = *(const float4*)p;
    const float4 b = *(const float4*)(p + 4);
    s16x8 r;
    r[0] = (short)f2b(a.x); r[1] = (short)f2b(a.y);
    r[2] = (short)f2b(a.z); r[3] = (short)f2b(a.w);
    r[4] = (short)f2b(b.x); r[5] = (short)f2b(b.y);
    r[6] = (short)f2b(b.z); r[7] = (short)f2b(b.w);
    return r;
}

// Single kernel, 256 blocks x 256 threads (all co-resident: 35.5 KB LDS,
// ~84 VGPR => >=2 blocks/CU capacity, grid == CU count).
// Phase A == R5 k_proj: blocks [0,128) qs from x; [128,256) ks+vT from c.
// Hand-rolled device barrier (atomicAdd + spin, agent scope).
// Phase B == R5 k_main: 8 n-rows/block, scores->swizzled LDS->PV MFMA->LN.
__global__ __launch_bounds__(256) void k_fused(
    const float* __restrict__ x, const float* __restrict__ c,
    const float* __restrict__ mask,
    const float* __restrict__ Wq, const float* __restrict__ bq,
    const float* __restrict__ Wk, const float* __restrict__ Wr,
    const float* __restrict__ Wv, const float* __restrict__ bv,
    const float* __restrict__ gamma, const float* __restrict__ beta,
    float* __restrict__ qs, float* __restrict__ ks,
    unsigned short* __restrict__ vT, int* __restrict__ flag,
    float* __restrict__ out)
{
    __shared__ unsigned short w_lds[16][512];   // 16 KB
    __shared__ float ksm[MM];                   // 2 KB
    __shared__ float h_lds[16][264];            // 16.9 KB
    __shared__ float red[4][16];

    const int tid  = threadIdx.x;
    const int lane = tid & 63, w = tid >> 6;
    const int li   = lane & 15, g = lane >> 4;

    // ================= Phase A: projections =================
    {
        const bool isk = blockIdx.x >= 128;
        const int row0 = (blockIdx.x & 127) << 4;
        const float* __restrict__ src = isk ? c : x;

        const float* ap = src + (size_t)(row0 + li) * DD + g * 8;
        s16x8 af[8];
        #pragma unroll
        for (int kk = 0; kk < 8; ++kk) af[kk] = cvt8(ap + kk * 32);

        const int e_base = w * 64 + li;

        if (!isk) {
            f32x4 acc[4];
            const float* bp[4];
            #pragma unroll
            for (int nt = 0; nt < 4; ++nt) {
                acc[nt] = (f32x4){0.f, 0.f, 0.f, 0.f};
                bp[nt] = Wq + (size_t)(e_base + nt * 16) * DD + g * 8;
            }
            #pragma unroll
            for (int kk = 0; kk < 8; ++kk)
                #pragma unroll
                for (int nt = 0; nt < 4; ++nt)
                    acc[nt] = mfma16(af[kk], cvt8(bp[nt] + kk * 32), acc[nt]);

            float p[4] = {0.f, 0.f, 0.f, 0.f};
            #pragma unroll
            for (int nt = 0; nt < 4; ++nt) {
                const int e = e_base + nt * 16;
                const float bqe = bq[e], wre = Wr[e];
                #pragma unroll
                for (int r = 0; r < 4; ++r)
                    p[r] += wre * tanhf(acc[nt][r] + bqe);
            }
            #pragma unroll
            for (int r = 0; r < 4; ++r) {
                p[r] += __shfl_xor(p[r], 1);
                p[r] += __shfl_xor(p[r], 2);
                p[r] += __shfl_xor(p[r], 4);
                p[r] += __shfl_xor(p[r], 8);
            }
            if (li == 0) {
                #pragma unroll
                for (int r = 0; r < 4; ++r) red[w][g * 4 + r] = p[r];
            }
            __syncthreads();
            if (tid < 16)
                qs[row0 + tid] = red[0][tid] + red[1][tid] + red[2][tid] + red[3][tid];
        } else {
            f32x4 ak[4], av[4];
            const float* bpk[4];
            const float* bpv[4];
            #pragma unroll
            for (int nt = 0; nt < 4; ++nt) {
                ak[nt] = (f32x4){0.f, 0.f, 0.f, 0.f};
                av[nt] = (f32x4){0.f, 0.f, 0.f, 0.f};
                bpk[nt] = Wk + (size_t)(e_base + nt * 16) * DD + g * 8;
                bpv[nt] = Wv + (size_t)(e_base + nt * 16) * DD + g * 8;
            }
            #pragma unroll
            for (int kk = 0; kk < 8; ++kk)
                #pragma unroll
                for (int nt = 0; nt < 4; ++nt) {
                    ak[nt] = mfma16(af[kk], cvt8(bpk[nt] + kk * 32), ak[nt]);
                    av[nt] = mfma16(af[kk], cvt8(bpv[nt] + kk * 32), av[nt]);
                }

            const int b  = row0 >> 9;
            const int m0 = row0 & 511;
            unsigned short* vTb = vT + (size_t)b * (DD * MM);
            #pragma unroll
            for (int nt = 0; nt < 4; ++nt) {
                const int e = e_base + nt * 16;
                const float bve = bv[e];
                u16x4 o;
                #pragma unroll
                for (int r = 0; r < 4; ++r)
                    o[r] = f2b((av[nt][r] + bve) * 0.0625f);  // 1/sqrt(256)
                *(u16x4*)(vTb + (size_t)e * MM + m0 + g * 4) = o;
            }

            float p[4] = {0.f, 0.f, 0.f, 0.f};
            #pragma unroll
            for (int nt = 0; nt < 4; ++nt) {
                const int e = e_base + nt * 16;
                const float wre = Wr[e];
                #pragma unroll
                for (int r = 0; r < 4; ++r)
                    p[r] += wre * tanhf(ak[nt][r]);
            }
            #pragma unroll
            for (int r = 0; r < 4; ++r) {
                p[r] += __shfl_xor(p[r], 1);
                p[r] += __shfl_xor(p[r], 2);
                p[r] += __shfl_xor(p[r], 4);
                p[r] += __shfl_xor(p[r], 8);
            }
            if (li == 0) {
                #pragma unroll
                for (int r = 0; r < 4; ++r) red[w][g * 4 + r] = p[r];
            }
            __syncthreads();
            if (tid < 16)
                ks[row0 + tid] = red[0][tid] + red[1][tid] + red[2][tid] + red[3][tid];
        }
    }

    // ================= device barrier (release -> spin -> acquire) ========
    __threadfence();            // per-thread device-scope release of qs/ks/vT
    __syncthreads();
    if (tid == 0) {
        __hip_atomic_fetch_add(flag, 1, __ATOMIC_RELEASE, __HIP_MEMORY_SCOPE_AGENT);
        while (__hip_atomic_load(flag, __ATOMIC_ACQUIRE, __HIP_MEMORY_SCOPE_AGENT) < 256)
            __builtin_amdgcn_s_sleep(1);
    }
    __syncthreads();
    __threadfence();            // acquire side for all threads

    // ================= Phase B: scores + PV + residual + LN =================
    {
        const int n0g = blockIdx.x << 3;    // 8 rows per block
        const int b   = n0g >> 9;

        ksm[tid]       = ks[(b << 9) + tid];
        ksm[tid + 256] = ks[(b << 9) + 256 + tid];
        __syncthreads();

        // scores rows 0..7 -> bf16 swizzled LDS (byte ^= (row&7)<<4)
        char* wbase = (char*)w_lds;
        const float* __restrict__ mrow = mask + (size_t)n0g * MM;
        #pragma unroll
        for (int it = 0; it < 16; ++it) {
            const int i = it >> 1;
            const int m = ((it & 1) << 8) + tid;
            const float qv = qs[n0g + i];
            float s = fmaxf(tanhf(qv + ksm[m]), 0.f) * mrow[(size_t)i * MM + m];
            *(unsigned short*)(wbase + (i << 10) + ((m << 1) ^ ((i & 7) << 4))) = f2b(s);
        }
        __syncthreads();

        // PV: wave w covers e-cols [w*64, w*64+64), K = 512 (16 k-steps).
        // A-tile rows 8..15 stale garbage; their D-rows are never consumed.
        f32x4 acc[4];
        const unsigned short* vp[4];
        #pragma unroll
        for (int nt = 0; nt < 4; ++nt) {
            acc[nt] = (f32x4){0.f, 0.f, 0.f, 0.f};
            vp[nt] = vT + (size_t)b * (DD * MM)
                        + (size_t)(w * 64 + nt * 16 + li) * MM + g * 8;
        }
        const char* arow = wbase + (li << 10);
        const int aswz = (li & 7) << 4;
        #pragma unroll
        for (int kk = 0; kk < 16; ++kk) {
            const s16x8 a = *(const s16x8*)(arow + (((kk << 6) + (g << 4)) ^ aswz));
            #pragma unroll
            for (int nt = 0; nt < 4; ++nt)
                acc[nt] = mfma16(a, *(const s16x8*)(vp[nt] + kk * 32), acc[nt]);
        }

        // scatter partial h: lane holds D-rows 4g+r, col e
        #pragma unroll
        for (int nt = 0; nt < 4; ++nt) {
            const int e = w * 64 + nt * 16 + li;
            #pragma unroll
            for (int r = 0; r < 4; ++r)
                h_lds[g * 4 + r][e] = acc[nt][r];
        }
        __syncthreads();

        // LN: wave w owns rows {2w, 2w+1}; lane owns 4 contiguous d
        const float4 gm = ((const float4*)gamma)[lane];
        const float4 bt = ((const float4*)beta)[lane];
        #pragma unroll
        for (int rr = 0; rr < 2; ++rr) {
            const int row = (w << 1) + rr;
            const float4 hv = *(const float4*)&h_lds[row][lane << 2];
            const float4 xv = *(const float4*)(x + ((size_t)(n0g + row)) * DD + (lane << 2));
            float4 h;
            h.x = xv.x + hv.x; h.y = xv.y + hv.y;
            h.z = xv.z + hv.z; h.w = xv.w + hv.w;
            float s  = h.x + h.y + h.z + h.w;
            float s2 = h.x * h.x + h.y * h.y + h.z * h.z + h.w * h.w;
            #pragma unroll
            for (int off = 32; off; off >>= 1) {
                s  += __shfl_xor(s, off);
                s2 += __shfl_xor(s2, off);
            }
            const float mean = s * (1.0f / DD);
            const float var  = s2 * (1.0f / DD) - mean * mean;
            const float inv  = rsqrtf(var + 1e-5f);
            float4 o;
            o.x = (h.x - mean) * inv * gm.x + bt.x;
            o.y = (h.y - mean) * inv * gm.y + bt.y;
            o.z = (h.z - mean) * inv * gm.z + bt.z;
            o.w = (h.w - mean) * inv * gm.w + bt.w;
            *(float4*)(out + ((size_t)(n0g + row)) * DD + (lane << 2)) = o;
        }
    }
}

extern "C" void kernel_launch(void* const* d_in, const int* in_sizes, int n_in,
                              void* d_out, int out_size, void* d_ws, size_t ws_size,
                              hipStream_t stream) {
    const float* x     = (const float*)d_in[0];
    const float* c     = (const float*)d_in[1];
    const float* mask  = (const float*)d_in[2];
    const float* Wq    = (const float*)d_in[3];
    const float* bq    = (const float*)d_in[4];
    const float* Wk    = (const float*)d_in[5];
    const float* Wr    = (const float*)d_in[6];
    const float* Wv    = (const float*)d_in[7];
    const float* bv    = (const float*)d_in[8];
    const float* gamma = (const float*)d_in[9];
    const float* beta  = (const float*)d_in[10];
    float* out = (float*)d_out;

    float* ws = (float*)d_ws;
    float* qs  = ws;                                    // 2048 f32
    float* ksb = ws + 2048;                             // 2048 f32
    unsigned short* vT = (unsigned short*)(ws + 4096);  // 524288 bf16 [b][e][m]
    int* flag = (int*)((char*)d_ws + 4096 * 4 + 524288 * 2);  // after vT

    hipMemsetAsync(flag, 0, 4, stream);   // deterministic barrier state per launch
    k_fused<<<256, 256, 0, stream>>>(x, c, mask, Wq, bq, Wk, Wr, Wv, bv,
                                     gamma, beta, qs, ksb, vT, flag, out);
}

// Round 9
// 36.239 us; speedup vs baseline: 2.6320x; 2.6320x over previous
//
#include <hip/hip_runtime.h>
#include <math.h>

// Problem sizes (fixed): B=4, N=512, M=512, D=256
#define BB 4
#define NN 512
#define MM 512
#define DD 256

typedef short  s16x8  __attribute__((ext_vector_type(8)));
typedef __bf16 bf16x8 __attribute__((ext_vector_type(8)));
typedef __bf16 bf16x4 __attribute__((ext_vector_type(4)));
typedef float  f32x4  __attribute__((ext_vector_type(4)));
typedef float  f32x8  __attribute__((ext_vector_type(8)));
typedef unsigned short u16x4 __attribute__((ext_vector_type(4)));

static __device__ __forceinline__ f32x4 mfma16(s16x8 a, s16x8 b, f32x4 c) {
    return __builtin_amdgcn_mfma_f32_16x16x32_bf16(
        __builtin_bit_cast(bf16x8, a), __builtin_bit_cast(bf16x8, b), c, 0, 0, 0);
}

// load 8 consecutive f32 (32B-aligned) -> bf16 fragment via v_cvt_pk_bf16_f32
static __device__ __forceinline__ s16x8 cvt8(const float* __restrict__ p) {
    const float4 a = *(const float4*)p;
    const float4 b = *(const float4*)(p + 4);
    f32x8 f;
    f[0] = a.x; f[1] = a.y; f[2] = a.z; f[3] = a.w;
    f[4] = b.x; f[5] = b.y; f[6] = b.z; f[7] = b.w;
    return __builtin_bit_cast(s16x8, __builtin_convertvector(f, bf16x8));
}

// 4 floats -> 4 bf16 (RNE)
static __device__ __forceinline__ u16x4 cvt4(float x, float y, float z, float w) {
    f32x4 f; f[0] = x; f[1] = y; f[2] = z; f[3] = w;
    return __builtin_bit_cast(u16x4, __builtin_convertvector(f, bf16x4));
}

// tanh(x) = 1 - 2/(exp2(2*log2e*x)+1); ~1e-6 abs err, 5 ops
static __device__ __forceinline__ float tanh_fast(float x) {
    const float e = __builtin_amdgcn_exp2f(x * 2.8853900817779268f);
    return fmaf(-2.0f, __builtin_amdgcn_rcpf(e + 1.0f), 1.0f);
}

// ---------------- kernel 1: MFMA projections (f32 in, bf16 in-register) ----
// blocks [0,128):  qs for 16 x-rows each; [128,256): ks + vT for 16 c-rows.
// Block: 256 thr = 4 waves; wave w covers e-cols [w*64, w*64+64).
__global__ __launch_bounds__(256) void k_proj(
    const float* __restrict__ x, const float* __restrict__ c,
    const float* __restrict__ Wq, const float* __restrict__ bq,
    const float* __restrict__ Wk, const float* __restrict__ Wr,
    const float* __restrict__ Wv, const float* __restrict__ bv,
    float* __restrict__ qs, float* __restrict__ ks,
    unsigned short* __restrict__ vT)
{
    __shared__ float red[4][16];
    const int tid  = threadIdx.x;
    const int lane = tid & 63, w = tid >> 6;
    const int li   = lane & 15, g = lane >> 4;
    const bool isk = blockIdx.x >= 128;
    const int row0 = (blockIdx.x & 127) << 4;
    const float* __restrict__ src = isk ? c : x;

    // A fragments: lane supplies A[i=li][k=g*8+t] for each of 8 k-steps
    const float* ap = src + (size_t)(row0 + li) * DD + g * 8;
    s16x8 af[8];
    #pragma unroll
    for (int kk = 0; kk < 8; ++kk) af[kk] = cvt8(ap + kk * 32);

    const int e_base = w * 64 + li;

    if (!isk) {
        f32x4 acc[4];
        const float* bp[4];
        #pragma unroll
        for (int nt = 0; nt < 4; ++nt) {
            acc[nt] = (f32x4){0.f, 0.f, 0.f, 0.f};
            bp[nt] = Wq + (size_t)(e_base + nt * 16) * DD + g * 8;
        }
        #pragma unroll
        for (int kk = 0; kk < 8; ++kk)
            #pragma unroll
            for (int nt = 0; nt < 4; ++nt)
                acc[nt] = mfma16(af[kk], cvt8(bp[nt] + kk * 32), acc[nt]);

        float p[4] = {0.f, 0.f, 0.f, 0.f};
        #pragma unroll
        for (int nt = 0; nt < 4; ++nt) {
            const int e = e_base + nt * 16;
            const float bqe = bq[e], wre = Wr[e];
            #pragma unroll
            for (int r = 0; r < 4; ++r)
                p[r] += wre * tanh_fast(acc[nt][r] + bqe);
        }
        #pragma unroll
        for (int r = 0; r < 4; ++r) {
            p[r] += __shfl_xor(p[r], 1);
            p[r] += __shfl_xor(p[r], 2);
            p[r] += __shfl_xor(p[r], 4);
            p[r] += __shfl_xor(p[r], 8);
        }
        if (li == 0) {
            #pragma unroll
            for (int r = 0; r < 4; ++r) red[w][g * 4 + r] = p[r];
        }
        __syncthreads();
        if (tid < 16)
            qs[row0 + tid] = red[0][tid] + red[1][tid] + red[2][tid] + red[3][tid];
    } else {
        f32x4 ak[4], av[4];
        const float* bpk[4];
        const float* bpv[4];
        #pragma unroll
        for (int nt = 0; nt < 4; ++nt) {
            ak[nt] = (f32x4){0.f, 0.f, 0.f, 0.f};
            av[nt] = (f32x4){0.f, 0.f, 0.f, 0.f};
            bpk[nt] = Wk + (size_t)(e_base + nt * 16) * DD + g * 8;
            bpv[nt] = Wv + (size_t)(e_base + nt * 16) * DD + g * 8;
        }
        #pragma unroll
        for (int kk = 0; kk < 8; ++kk)
            #pragma unroll
            for (int nt = 0; nt < 4; ++nt) {
                ak[nt] = mfma16(af[kk], cvt8(bpk[nt] + kk * 32), ak[nt]);
                av[nt] = mfma16(af[kk], cvt8(bpv[nt] + kk * 32), av[nt]);
            }

        // vT[b][e][m] bf16: lane holds m-rows m0+4g+r for col e
        const int b  = row0 >> 9;
        const int m0 = row0 & 511;
        unsigned short* vTb = vT + (size_t)b * (DD * MM);
        #pragma unroll
        for (int nt = 0; nt < 4; ++nt) {
            const int e = e_base + nt * 16;
            const float bve = bv[e];
            const u16x4 o = cvt4((av[nt][0] + bve) * 0.0625f,
                                 (av[nt][1] + bve) * 0.0625f,
                                 (av[nt][2] + bve) * 0.0625f,
                                 (av[nt][3] + bve) * 0.0625f);  // 1/sqrt(256)
            *(u16x4*)(vTb + (size_t)e * MM + m0 + g * 4) = o;
        }

        float p[4] = {0.f, 0.f, 0.f, 0.f};
        #pragma unroll
        for (int nt = 0; nt < 4; ++nt) {
            const int e = e_base + nt * 16;
            const float wre = Wr[e];
            #pragma unroll
            for (int r = 0; r < 4; ++r)
                p[r] += wre * tanh_fast(ak[nt][r]);
        }
        #pragma unroll
        for (int r = 0; r < 4; ++r) {
            p[r] += __shfl_xor(p[r], 1);
            p[r] += __shfl_xor(p[r], 2);
            p[r] += __shfl_xor(p[r], 4);
            p[r] += __shfl_xor(p[r], 8);
        }
        if (li == 0) {
            #pragma unroll
            for (int r = 0; r < 4; ++r) red[w][g * 4 + r] = p[r];
        }
        __syncthreads();
        if (tid < 16)
            ks[row0 + tid] = red[0][tid] + red[1][tid] + red[2][tid] + red[3][tid];
    }
}

// ---------------- kernel 2: scores + PV (MFMA) + residual + LayerNorm -----
// 256 blocks x 8 n-rows (all CUs active). LDS score tile bf16 XOR-swizzled.
// MFMA A-tile rows 8..15 are stale LDS garbage; their D-rows never read.
__global__ __launch_bounds__(256) void k_main(
    const float* __restrict__ x, const float* __restrict__ mask,
    const float* __restrict__ qs, const float* __restrict__ ks,
    const unsigned short* __restrict__ vT,
    const float* __restrict__ gamma, const float* __restrict__ beta,
    float* __restrict__ out)
{
    __shared__ unsigned short w_lds[16][512];   // 16 KB (rows 0..7 written)
    __shared__ float ksm[MM];                   // 2 KB
    __shared__ float h_lds[16][264];            // stride 264: 2-way write alias (free)
    const int tid  = threadIdx.x;
    const int lane = tid & 63, w = tid >> 6;
    const int li   = lane & 15, g = lane >> 4;
    const int n0g  = blockIdx.x << 3;           // 8 rows per block
    const int b    = n0g >> 9;

    ksm[tid]       = ks[(b << 9) + tid];
    ksm[tid + 256] = ks[(b << 9) + 256 + tid];
    __syncthreads();

    // scores rows 0..7 -> bf16 swizzled LDS (byte ^= (row&7)<<4), 4 m/thread/iter
    char* wbase = (char*)w_lds;
    const float* __restrict__ mrow = mask + (size_t)n0g * MM;
    #pragma unroll
    for (int it = 0; it < 4; ++it) {
        const int L = (it << 10) + (tid << 2);
        const int i = L >> 9;
        const int m = L & 511;
        const float qv = qs[n0g + i];
        const float4 mk = *(const float4*)(mrow + (size_t)i * MM + m);
        const float4 kv = *(const float4*)&ksm[m];
        const u16x4 o = cvt4(fmaxf(tanh_fast(qv + kv.x), 0.f) * mk.x,
                             fmaxf(tanh_fast(qv + kv.y), 0.f) * mk.y,
                             fmaxf(tanh_fast(qv + kv.z), 0.f) * mk.z,
                             fmaxf(tanh_fast(qv + kv.w), 0.f) * mk.w);
        *(u16x4*)(wbase + (i << 10) + ((m << 1) ^ ((i & 7) << 4))) = o;
    }
    __syncthreads();

    // PV: wave w covers e-cols [w*64, w*64+64), K = 512 (16 k-steps)
    f32x4 acc[4];
    const unsigned short* vp[4];
    #pragma unroll
    for (int nt = 0; nt < 4; ++nt) {
        acc[nt] = (f32x4){0.f, 0.f, 0.f, 0.f};
        vp[nt] = vT + (size_t)b * (DD * MM)
                    + (size_t)(w * 64 + nt * 16 + li) * MM + g * 8;
    }
    const char* arow = wbase + (li << 10);
    const int aswz = (li & 7) << 4;
    #pragma unroll
    for (int kk = 0; kk < 16; ++kk) {
        const s16x8 a = *(const s16x8*)(arow + (((kk << 6) + (g << 4)) ^ aswz));
        #pragma unroll
        for (int nt = 0; nt < 4; ++nt)
            acc[nt] = mfma16(a, *(const s16x8*)(vp[nt] + kk * 32), acc[nt]);
    }

    // scatter partial h: lane holds D-rows 4g+r, col e
    #pragma unroll
    for (int nt = 0; nt < 4; ++nt) {
        const int e = w * 64 + nt * 16 + li;
        #pragma unroll
        for (int r = 0; r < 4; ++r)
            h_lds[g * 4 + r][e] = acc[nt][r];
    }
    __syncthreads();

    // LN: wave w owns rows {2w, 2w+1}; lane owns 4 contiguous d
    const float4 gm = ((const float4*)gamma)[lane];
    const float4 bt = ((const float4*)beta)[lane];
    #pragma unroll
    for (int rr = 0; rr < 2; ++rr) {
        const int row = (w << 1) + rr;
        const float4 hv = *(const float4*)&h_lds[row][lane << 2];
        const float4 xv = *(const float4*)(x + ((size_t)(n0g + row)) * DD + (lane << 2));
        float4 h;
        h.x = xv.x + hv.x; h.y = xv.y + hv.y;
        h.z = xv.z + hv.z; h.w = xv.w + hv.w;
        float s  = h.x + h.y + h.z + h.w;
        float s2 = h.x * h.x + h.y * h.y + h.z * h.z + h.w * h.w;
        #pragma unroll
        for (int off = 32; off; off >>= 1) {
            s  += __shfl_xor(s, off);
            s2 += __shfl_xor(s2, off);
        }
        const float mean = s * (1.0f / DD);
        const float var  = s2 * (1.0f / DD) - mean * mean;
        const float inv  = rsqrtf(var + 1e-5f);
        float4 o;
        o.x = (h.x - mean) * inv * gm.x + bt.x;
        o.y = (h.y - mean) * inv * gm.y + bt.y;
        o.z = (h.z - mean) * inv * gm.z + bt.z;
        o.w = (h.w - mean) * inv * gm.w + bt.w;
        *(float4*)(out + ((size_t)(n0g + row)) * DD + (lane << 2)) = o;
    }
}

extern "C" void kernel_launch(void* const* d_in, const int* in_sizes, int n_in,
                              void* d_out, int out_size, void* d_ws, size_t ws_size,
                              hipStream_t stream) {
    const float* x     = (const float*)d_in[0];
    const float* c     = (const float*)d_in[1];
    const float* mask  = (const float*)d_in[2];
    const float* Wq    = (const float*)d_in[3];
    const float* bq    = (const float*)d_in[4];
    const float* Wk    = (const float*)d_in[5];
    const float* Wr    = (const float*)d_in[6];
    const float* Wv    = (const float*)d_in[7];
    const float* bv    = (const float*)d_in[8];
    const float* gamma = (const float*)d_in[9];
    const float* beta  = (const float*)d_in[10];
    float* out = (float*)d_out;

    float* ws = (float*)d_ws;
    float* qs  = ws;                                    // 2048 f32
    float* ksb = ws + 2048;                             // 2048 f32
    unsigned short* vT = (unsigned short*)(ws + 4096);  // 524288 bf16 [b][e][m]

    k_proj<<<256, 256, 0, stream>>>(x, c, Wq, bq, Wk, Wr, Wv, bv, qs, ksb, vT);
    k_main<<<256, 256, 0, stream>>>(x, mask, qs, ksb, vT, gamma, beta, out);
}